// Round 1
// baseline (89836.047 us; speedup 1.0000x reference)
//
#include <hip/hip_runtime.h>
#include <hip/hip_bf16.h>
#include <hip/hip_cooperative_groups.h>

namespace cg = cooperative_groups;

// Problem constants
#define TSTEPS 1024
#define HDIM   1024
#define INDIM  512
#define NGATE  4096   // 4*HDIM

// ---------------------------------------------------------------------------
// GEMM: C[t][n] = sum_k A[t][k] * B[n][k] + bias1[n] + bias2[n]
// A: M x K row-major (mode 0) or virtual concat(x, time) (mode 1, K=513)
// B: N x K row-major (the W_ih matrices)
// M=1024, N=4096. Tiles: 64x64x32, 256 threads, 4x4 micro-tile per thread.
// ---------------------------------------------------------------------------
#define BM 64
#define BN 64
#define BK 32

__global__ __launch_bounds__(256) void gemm_tn(
    const float* __restrict__ A,
    const float* __restrict__ B,
    const float* __restrict__ bias1,
    const float* __restrict__ bias2,
    float* __restrict__ C,
    int M, int N, int K,
    const float* __restrict__ x,
    const float* __restrict__ timev,
    int mode)
{
    __shared__ float As[BK][BM + 4];  // +4 pad: breaks bank conflicts, keeps 16B align
    __shared__ float Bs[BK][BN + 4];

    const int tid = threadIdx.x;
    const int mblocks = M / BM;
    const int bm = blockIdx.x % mblocks;
    const int bn = blockIdx.x / mblocks;
    const int t0 = bm * BM;
    const int n0 = bn * BN;

    const int tx = tid & 15;   // n-dir
    const int ty = tid >> 4;   // m-dir

    float acc[4][4] = {{0.f}};

    for (int kc = 0; kc < K; kc += BK) {
        // Load A tile (64x32) and B tile (64x32); 2048 elems each, 8 per thread.
#pragma unroll
        for (int i = 0; i < 8; i++) {
            int idx = tid + i * 256;
            int r = idx >> 5;     // 0..63
            int c = idx & 31;     // 0..31
            int col = kc + c;
            float av;
            int trow = t0 + r;
            if (mode == 1) {
                av = (col < INDIM) ? x[(size_t)trow * INDIM + col]
                                   : ((col == INDIM) ? timev[trow] : 0.f);
            } else {
                av = (col < K) ? A[(size_t)trow * K + col] : 0.f;
            }
            As[c][r] = av;
            int nrow = n0 + r;
            Bs[c][r] = (col < K) ? B[(size_t)nrow * K + col] : 0.f;
        }
        __syncthreads();

#pragma unroll
        for (int kk = 0; kk < BK; kk++) {
            float a[4], b[4];
#pragma unroll
            for (int i = 0; i < 4; i++) a[i] = As[kk][ty * 4 + i];
#pragma unroll
            for (int j = 0; j < 4; j++) b[j] = Bs[kk][tx * 4 + j];
#pragma unroll
            for (int i = 0; i < 4; i++)
#pragma unroll
                for (int j = 0; j < 4; j++)
                    acc[i][j] = fmaf(a[i], b[j], acc[i][j]);
        }
        __syncthreads();
    }

#pragma unroll
    for (int i = 0; i < 4; i++) {
        int trow = t0 + ty * 4 + i;
#pragma unroll
        for (int j = 0; j < 4; j++) {
            int n = n0 + tx * 4 + j;
            C[(size_t)trow * N + n] = acc[i][j] + bias1[n] + bias2[n];
        }
    }
}

// ---------------------------------------------------------------------------
// Persistent LSTM scan (one layer): 256 WGs x 256 threads, cooperative.
// WG w owns hidden units u0=4w..4w+3 (16 gate rows). Each thread holds 64
// W_hh weights in VGPRs: row = g*1024 + u0 + q, cols j*16+seg.
// Per tick: stage h_{t-1} to LDS, dot, 16-lane shuffle reduce, cell math on
// wave q (= unit q), lane 0 writes h_t. grid.sync() per tick.
// ---------------------------------------------------------------------------
__global__ __launch_bounds__(256) void lstm_scan(
    const float* __restrict__ Whh,   // 4096 x 1024 row-major
    const float* __restrict__ G,     // T x 4096 precomputed gate inputs
    const float* __restrict__ h0,    // 1024
    const float* __restrict__ c0,    // 1024
    float* __restrict__ Hout)        // T x 1024
{
    cg::grid_group grid = cg::this_grid();
    __shared__ float hs[HDIM];

    const int tid = threadIdx.x;
    const int u0 = blockIdx.x * 4;
    const int row_local = tid >> 4;      // 0..15 = q*4+g
    const int seg = tid & 15;
    const int q = row_local >> 2;        // unit within WG == wave index
    const int g = row_local & 3;         // gate (i,f,g,o)
    const int grow = g * HDIM + u0 + q;  // global gate row

    float wreg[64];
    {
        const float* wrow = Whh + (size_t)grow * HDIM;
#pragma unroll
        for (int j = 0; j < 64; j++) wreg[j] = wrow[j * 16 + seg];
    }

    float c = c0[u0 + q];

    for (int t = 0; t < TSTEPS; t++) {
        const float* hprev = (t == 0) ? h0 : (Hout + (size_t)(t - 1) * HDIM);
        hs[tid]        = hprev[tid];
        hs[tid + 256]  = hprev[tid + 256];
        hs[tid + 512]  = hprev[tid + 512];
        hs[tid + 768]  = hprev[tid + 768];
        float Gval = G[(size_t)t * NGATE + grow];   // independent of h: issue early
        __syncthreads();

        float a0 = 0.f, a1 = 0.f, a2 = 0.f, a3 = 0.f;
#pragma unroll
        for (int j = 0; j < 64; j += 4) {
            a0 = fmaf(wreg[j],     hs[(j    ) * 16 + seg], a0);
            a1 = fmaf(wreg[j + 1], hs[(j + 1) * 16 + seg], a1);
            a2 = fmaf(wreg[j + 2], hs[(j + 2) * 16 + seg], a2);
            a3 = fmaf(wreg[j + 3], hs[(j + 3) * 16 + seg], a3);
        }
        float acc = (a0 + a1) + (a2 + a3);
        acc += __shfl_down(acc, 8, 16);
        acc += __shfl_down(acc, 4, 16);
        acc += __shfl_down(acc, 2, 16);
        acc += __shfl_down(acc, 1, 16);
        float gate = acc + Gval;            // valid on seg==0 lanes (0,16,32,48)

        float gi = __shfl(gate, 0, 64);
        float gf = __shfl(gate, 16, 64);
        float gg = __shfl(gate, 32, 64);
        float go = __shfl(gate, 48, 64);

        float i_ = 1.f / (1.f + __expf(-gi));
        float f_ = 1.f / (1.f + __expf(-gf));
        float g_ = tanhf(gg);
        float o_ = 1.f / (1.f + __expf(-go));
        c = f_ * c + i_ * g_;
        float hn = o_ * tanhf(c);

        if ((tid & 63) == 0) Hout[(size_t)t * HDIM + u0 + q] = hn;

        grid.sync();
    }
}

// ---------------------------------------------------------------------------
// Attention
// ---------------------------------------------------------------------------
__global__ __launch_bounds__(256) void attn_dot(
    const float* __restrict__ H3, float* __restrict__ attn)
{
    const int t = blockIdx.x * 4 + (threadIdx.x >> 6);
    const int lane = threadIdx.x & 63;
    const float* hrow = H3 + (size_t)t * HDIM;
    const float* hf = H3 + (size_t)(TSTEPS - 1) * HDIM;
    float p = 0.f;
    for (int j = lane; j < HDIM; j += 64) p = fmaf(hrow[j], hf[j], p);
#pragma unroll
    for (int d = 32; d; d >>= 1) p += __shfl_down(p, d, 64);
    if (lane == 0) attn[t] = p;
}

__global__ __launch_bounds__(64) void softmax_1024(float* attn)
{
    const int lane = threadIdx.x;   // 64 threads, single wave
    float vals[16];
    float m = -1e30f;
#pragma unroll
    for (int i = 0; i < 16; i++) {
        vals[i] = attn[lane + i * 64];
        m = fmaxf(m, vals[i]);
    }
#pragma unroll
    for (int d = 32; d; d >>= 1) m = fmaxf(m, __shfl_xor(m, d, 64));
    float s = 0.f;
#pragma unroll
    for (int i = 0; i < 16; i++) {
        vals[i] = expf(vals[i] - m);
        s += vals[i];
    }
#pragma unroll
    for (int d = 32; d; d >>= 1) s += __shfl_xor(s, d, 64);
    float inv = 1.f / s;
#pragma unroll
    for (int i = 0; i < 16; i++) attn[lane + i * 64] = vals[i] * inv;
}

__global__ __launch_bounds__(256) void context_kernel(
    const float* __restrict__ H3, const float* __restrict__ w,
    float* __restrict__ out)
{
    const int u = blockIdx.x * 4 + (threadIdx.x >> 6);
    const int lane = threadIdx.x & 63;
    float p = 0.f;
    for (int t = lane; t < TSTEPS; t += 64)
        p = fmaf(H3[(size_t)t * HDIM + u], w[t], p);
#pragma unroll
    for (int d = 32; d; d >>= 1) p += __shfl_down(p, d, 64);
    if (lane == 0) out[u] = p;
}

// ---------------------------------------------------------------------------
// Launch
// ---------------------------------------------------------------------------
extern "C" void kernel_launch(void* const* d_in, const int* in_sizes, int n_in,
                              void* d_out, int out_size, void* d_ws, size_t ws_size,
                              hipStream_t stream)
{
    const float* x     = (const float*)d_in[0];
    const float* timev = (const float*)d_in[1];
    const float* h0_1  = (const float*)d_in[2];
    const float* c0_1  = (const float*)d_in[3];
    const float* h0_2  = (const float*)d_in[4];
    const float* c0_2  = (const float*)d_in[5];
    const float* h0_3  = (const float*)d_in[6];
    const float* c0_3  = (const float*)d_in[7];
    const float* Wih1  = (const float*)d_in[8];
    const float* Whh1  = (const float*)d_in[9];
    const float* bih1  = (const float*)d_in[10];
    const float* bhh1  = (const float*)d_in[11];
    const float* Wih2  = (const float*)d_in[12];
    const float* Whh2  = (const float*)d_in[13];
    const float* bih2  = (const float*)d_in[14];
    const float* bhh2  = (const float*)d_in[15];

    float* ws   = (float*)d_ws;
    float* G    = ws;                        // 1024*4096
    float* H1   = G + (size_t)TSTEPS * NGATE;
    float* H2   = H1 + (size_t)TSTEPS * HDIM;
    float* H3   = H2 + (size_t)TSTEPS * HDIM;
    float* attn = H3 + (size_t)TSTEPS * HDIM;
    float* out  = (float*)d_out;

    const dim3 gemm_grid(1024), blk256(256);

    // Layer 1: G = concat(x,time) @ Wih1^T + b ; then scan
    gemm_tn<<<gemm_grid, blk256, 0, stream>>>(nullptr, Wih1, bih1, bhh1, G,
                                              TSTEPS, NGATE, INDIM + 1, x, timev, 1);
    {
        const float* a0 = Whh1; const float* a1 = G; const float* a2 = h0_1;
        const float* a3 = c0_1; float* a4 = H1;
        void* args[] = {&a0, &a1, &a2, &a3, &a4};
        hipLaunchCooperativeKernel((void*)lstm_scan, dim3(256), dim3(256), args, 0, stream);
    }

    // Layer 2
    gemm_tn<<<gemm_grid, blk256, 0, stream>>>(H1, Wih2, bih2, bhh2, G,
                                              TSTEPS, NGATE, HDIM, nullptr, nullptr, 0);
    {
        const float* a0 = Whh2; const float* a1 = G; const float* a2 = h0_2;
        const float* a3 = c0_2; float* a4 = H2;
        void* args[] = {&a0, &a1, &a2, &a3, &a4};
        hipLaunchCooperativeKernel((void*)lstm_scan, dim3(256), dim3(256), args, 0, stream);
    }

    // Layer 3 (reference reuses layer-2 weights)
    gemm_tn<<<gemm_grid, blk256, 0, stream>>>(H2, Wih2, bih2, bhh2, G,
                                              TSTEPS, NGATE, HDIM, nullptr, nullptr, 0);
    {
        const float* a0 = Whh2; const float* a1 = G; const float* a2 = h0_3;
        const float* a3 = c0_3; float* a4 = H3;
        void* args[] = {&a0, &a1, &a2, &a3, &a4};
        hipLaunchCooperativeKernel((void*)lstm_scan, dim3(256), dim3(256), args, 0, stream);
    }

    // Attention
    attn_dot<<<dim3(256), blk256, 0, stream>>>(H3, attn);
    softmax_1024<<<dim3(1), dim3(64), 0, stream>>>(attn);
    context_kernel<<<dim3(256), blk256, 0, stream>>>(H3, attn, out);
}

// Round 2
// 21777.708 us; speedup vs baseline: 4.1251x; 4.1251x over previous
//
#include <hip/hip_runtime.h>
#include <hip/hip_bf16.h>

// Problem constants
#define TSTEPS 1024
#define HDIM   1024
#define INDIM  512
#define NGATE  4096   // 4*HDIM

// ---------------------------------------------------------------------------
// Device-scope (agent) memory helpers: compile to global_load/store with
// sc0 sc1 set -> bypass L1 and per-XCD L2, read/write the coherent LLC.
// This makes cross-workgroup h exchange correct WITHOUT any cache
// writeback/invalidate (the thing that made cg::grid.sync cost ~28us/tick).
// ---------------------------------------------------------------------------
__device__ __forceinline__ float agent_load(const float* p) {
    return __hip_atomic_load(const_cast<float*>(p), __ATOMIC_RELAXED,
                             __HIP_MEMORY_SCOPE_AGENT);
}
__device__ __forceinline__ void agent_store(float* p, float v) {
    __hip_atomic_store(p, v, __ATOMIC_RELAXED, __HIP_MEMORY_SCOPE_AGENT);
}

// ---------------------------------------------------------------------------
// GEMM: C[t][n] = sum_k A[t][k] * B[n][k] + bias1[n] + bias2[n]
// A: M x K row-major (mode 0) or virtual concat(x, time) (mode 1, K=513)
// B: N x K row-major (the W_ih matrices)
// M=1024, N=4096. Tiles: 64x64x32, 256 threads, 4x4 micro-tile per thread.
// ---------------------------------------------------------------------------
#define BM 64
#define BN 64
#define BK 32

__global__ __launch_bounds__(256) void gemm_tn(
    const float* __restrict__ A,
    const float* __restrict__ B,
    const float* __restrict__ bias1,
    const float* __restrict__ bias2,
    float* __restrict__ C,
    int M, int N, int K,
    const float* __restrict__ x,
    const float* __restrict__ timev,
    int mode)
{
    __shared__ float As[BK][BM + 4];
    __shared__ float Bs[BK][BN + 4];

    const int tid = threadIdx.x;
    const int mblocks = M / BM;
    const int bm = blockIdx.x % mblocks;
    const int bn = blockIdx.x / mblocks;
    const int t0 = bm * BM;
    const int n0 = bn * BN;

    const int tx = tid & 15;   // n-dir
    const int ty = tid >> 4;   // m-dir

    float acc[4][4] = {{0.f}};

    for (int kc = 0; kc < K; kc += BK) {
#pragma unroll
        for (int i = 0; i < 8; i++) {
            int idx = tid + i * 256;
            int r = idx >> 5;     // 0..63
            int c = idx & 31;     // 0..31
            int col = kc + c;
            float av;
            int trow = t0 + r;
            if (mode == 1) {
                av = (col < INDIM) ? x[(size_t)trow * INDIM + col]
                                   : ((col == INDIM) ? timev[trow] : 0.f);
            } else {
                av = (col < K) ? A[(size_t)trow * K + col] : 0.f;
            }
            As[c][r] = av;
            int nrow = n0 + r;
            Bs[c][r] = (col < K) ? B[(size_t)nrow * K + col] : 0.f;
        }
        __syncthreads();

#pragma unroll
        for (int kk = 0; kk < BK; kk++) {
            float a[4], b[4];
#pragma unroll
            for (int i = 0; i < 4; i++) a[i] = As[kk][ty * 4 + i];
#pragma unroll
            for (int j = 0; j < 4; j++) b[j] = Bs[kk][tx * 4 + j];
#pragma unroll
            for (int i = 0; i < 4; i++)
#pragma unroll
                for (int j = 0; j < 4; j++)
                    acc[i][j] = fmaf(a[i], b[j], acc[i][j]);
        }
        __syncthreads();
    }

#pragma unroll
    for (int i = 0; i < 4; i++) {
        int trow = t0 + ty * 4 + i;
#pragma unroll
        for (int j = 0; j < 4; j++) {
            int n = n0 + tx * 4 + j;
            C[(size_t)trow * N + n] = acc[i][j] + bias1[n] + bias2[n];
        }
    }
}

// ---------------------------------------------------------------------------
// Persistent LSTM scan (one layer): 256 WGs x 256 threads (co-resident via
// cooperative launch). WG w owns hidden units u0=4w..4w+3; wave q owns unit
// u0+q and computes ALL FOUR gate rows (shares each h load across 4 FMAs:
// 16 LDS reads/thread/tick instead of 64; lanes s and s+32 alias a bank
// 2-way which is free per m136).
//
// Cross-WG h exchange via agent-scope (sc0 sc1) loads/stores -> coherent LLC,
// no cache maintenance. Per-tick barrier: monotonic counter per tick,
// atomicAdd + spin by thread 0 only.
// ---------------------------------------------------------------------------
__global__ __launch_bounds__(256) void lstm_scan(
    const float* __restrict__ Whh,   // 4096 x 1024 row-major
    const float* __restrict__ G,     // T x 4096 precomputed gate inputs
    const float* __restrict__ h0,    // 1024
    const float* __restrict__ c0,    // 1024
    float* __restrict__ Hout,        // T x 1024
    unsigned* __restrict__ cnt)      // TSTEPS counters, pre-zeroed
{
    __shared__ float hs[HDIM];

    const int tid = threadIdx.x;
    const int u0 = blockIdx.x * 4;
    const int q = tid >> 6;          // unit within WG == wave index
    const int s = tid & 63;          // lane

    // wreg[g*16+m] = Whh[g*HDIM + u0 + q][s + m*64]
    float wreg[64];
#pragma unroll
    for (int g = 0; g < 4; g++) {
        const float* wrow = Whh + (size_t)(g * HDIM + u0 + q) * HDIM + s;
#pragma unroll
        for (int m = 0; m < 16; m++)
            wreg[g * 16 + m] = wrow[m * 64];
    }

    float c = c0[u0 + q];
    const float* hprev = h0;

    for (int t = 0; t < TSTEPS; t++) {
        // G values (wave-uniform addresses), issued early
        const float* gp = G + (size_t)t * NGATE + u0 + q;
        float Gv0 = gp[0 * HDIM];
        float Gv1 = gp[1 * HDIM];
        float Gv2 = gp[2 * HDIM];
        float Gv3 = gp[3 * HDIM];

        // stage h_{t-1} into LDS (agent-scope loads hit the coherent LLC)
        float v0 = agent_load(hprev + tid);
        float v1 = agent_load(hprev + tid + 256);
        float v2 = agent_load(hprev + tid + 512);
        float v3 = agent_load(hprev + tid + 768);
        hs[tid]       = v0;
        hs[tid + 256] = v1;
        hs[tid + 512] = v2;
        hs[tid + 768] = v3;
        __syncthreads();

        float a0 = 0.f, a1 = 0.f, a2 = 0.f, a3 = 0.f;
#pragma unroll
        for (int m = 0; m < 16; m++) {
            float hv = hs[s + m * 64];
            a0 = fmaf(wreg[0 * 16 + m], hv, a0);
            a1 = fmaf(wreg[1 * 16 + m], hv, a1);
            a2 = fmaf(wreg[2 * 16 + m], hv, a2);
            a3 = fmaf(wreg[3 * 16 + m], hv, a3);
        }
#pragma unroll
        for (int d = 1; d < 64; d <<= 1) {
            a0 += __shfl_xor(a0, d, 64);
            a1 += __shfl_xor(a1, d, 64);
            a2 += __shfl_xor(a2, d, 64);
            a3 += __shfl_xor(a3, d, 64);
        }

        float gi = a0 + Gv0;
        float gf = a1 + Gv1;
        float gg = a2 + Gv2;
        float go = a3 + Gv3;

        float i_ = 1.f / (1.f + __expf(-gi));
        float f_ = 1.f / (1.f + __expf(-gf));
        float g_ = tanhf(gg);
        float o_ = 1.f / (1.f + __expf(-go));
        c = f_ * c + i_ * g_;
        float hn = o_ * tanhf(c);

        if (s == 0)
            agent_store(Hout + (size_t)t * HDIM + u0 + q, hn);

        hprev = Hout + (size_t)t * HDIM;

        if (t + 1 < TSTEPS) {
            // __syncthreads drains vmcnt -> all 4 unit-stores of this WG are
            // at the LLC before thread 0 announces arrival.
            __syncthreads();
            if (tid == 0) {
                __hip_atomic_fetch_add(&cnt[t], 1u, __ATOMIC_RELEASE,
                                       __HIP_MEMORY_SCOPE_AGENT);
                while (__hip_atomic_load(&cnt[t], __ATOMIC_RELAXED,
                                         __HIP_MEMORY_SCOPE_AGENT) < 256u)
                    __builtin_amdgcn_s_sleep(1);
            }
            __syncthreads();
        }
    }
}

// ---------------------------------------------------------------------------
// Attention
// ---------------------------------------------------------------------------
__global__ __launch_bounds__(256) void attn_dot(
    const float* __restrict__ H3, float* __restrict__ attn)
{
    const int t = blockIdx.x * 4 + (threadIdx.x >> 6);
    const int lane = threadIdx.x & 63;
    const float* hrow = H3 + (size_t)t * HDIM;
    const float* hf = H3 + (size_t)(TSTEPS - 1) * HDIM;
    float p = 0.f;
    for (int j = lane; j < HDIM; j += 64) p = fmaf(hrow[j], hf[j], p);
#pragma unroll
    for (int d = 32; d; d >>= 1) p += __shfl_down(p, d, 64);
    if (lane == 0) attn[t] = p;
}

__global__ __launch_bounds__(64) void softmax_1024(float* attn)
{
    const int lane = threadIdx.x;   // 64 threads, single wave
    float vals[16];
    float m = -1e30f;
#pragma unroll
    for (int i = 0; i < 16; i++) {
        vals[i] = attn[lane + i * 64];
        m = fmaxf(m, vals[i]);
    }
#pragma unroll
    for (int d = 32; d; d >>= 1) m = fmaxf(m, __shfl_xor(m, d, 64));
    float s = 0.f;
#pragma unroll
    for (int i = 0; i < 16; i++) {
        vals[i] = expf(vals[i] - m);
        s += vals[i];
    }
#pragma unroll
    for (int d = 32; d; d >>= 1) s += __shfl_xor(s, d, 64);
    float inv = 1.f / s;
#pragma unroll
    for (int i = 0; i < 16; i++) attn[lane + i * 64] = vals[i] * inv;
}

__global__ __launch_bounds__(256) void context_kernel(
    const float* __restrict__ H3, const float* __restrict__ w,
    float* __restrict__ out)
{
    const int u = blockIdx.x * 4 + (threadIdx.x >> 6);
    const int lane = threadIdx.x & 63;
    float p = 0.f;
    for (int t = lane; t < TSTEPS; t += 64)
        p = fmaf(H3[(size_t)t * HDIM + u], w[t], p);
#pragma unroll
    for (int d = 32; d; d >>= 1) p += __shfl_down(p, d, 64);
    if (lane == 0) out[u] = p;
}

// ---------------------------------------------------------------------------
// Launch
// ---------------------------------------------------------------------------
extern "C" void kernel_launch(void* const* d_in, const int* in_sizes, int n_in,
                              void* d_out, int out_size, void* d_ws, size_t ws_size,
                              hipStream_t stream)
{
    const float* x     = (const float*)d_in[0];
    const float* timev = (const float*)d_in[1];
    const float* h0_1  = (const float*)d_in[2];
    const float* c0_1  = (const float*)d_in[3];
    const float* h0_2  = (const float*)d_in[4];
    const float* c0_2  = (const float*)d_in[5];
    const float* h0_3  = (const float*)d_in[6];
    const float* c0_3  = (const float*)d_in[7];
    const float* Wih1  = (const float*)d_in[8];
    const float* Whh1  = (const float*)d_in[9];
    const float* bih1  = (const float*)d_in[10];
    const float* bhh1  = (const float*)d_in[11];
    const float* Wih2  = (const float*)d_in[12];
    const float* Whh2  = (const float*)d_in[13];
    const float* bih2  = (const float*)d_in[14];
    const float* bhh2  = (const float*)d_in[15];

    float* ws   = (float*)d_ws;
    float* G    = ws;                        // 1024*4096
    float* H1   = G + (size_t)TSTEPS * NGATE;
    float* H2   = H1 + (size_t)TSTEPS * HDIM;
    float* H3   = H2 + (size_t)TSTEPS * HDIM;
    float* attn = H3 + (size_t)TSTEPS * HDIM;
    unsigned* cnt = (unsigned*)(attn + TSTEPS); // 3*TSTEPS counters
    float* out  = (float*)d_out;

    // zero the barrier counters (workspace is poisoned 0xAA before each call)
    hipMemsetAsync(cnt, 0, 3 * TSTEPS * sizeof(unsigned), stream);

    const dim3 gemm_grid(1024), blk256(256);

    // Layer 1: G = concat(x,time) @ Wih1^T + b ; then scan
    gemm_tn<<<gemm_grid, blk256, 0, stream>>>(nullptr, Wih1, bih1, bhh1, G,
                                              TSTEPS, NGATE, INDIM + 1, x, timev, 1);
    {
        const float* a0 = Whh1; const float* a1 = G; const float* a2 = h0_1;
        const float* a3 = c0_1; float* a4 = H1; unsigned* a5 = cnt;
        void* args[] = {&a0, &a1, &a2, &a3, &a4, &a5};
        hipLaunchCooperativeKernel((void*)lstm_scan, dim3(256), dim3(256), args, 0, stream);
    }

    // Layer 2
    gemm_tn<<<gemm_grid, blk256, 0, stream>>>(H1, Wih2, bih2, bhh2, G,
                                              TSTEPS, NGATE, HDIM, nullptr, nullptr, 0);
    {
        const float* a0 = Whh2; const float* a1 = G; const float* a2 = h0_2;
        const float* a3 = c0_2; float* a4 = H2; unsigned* a5 = cnt + TSTEPS;
        void* args[] = {&a0, &a1, &a2, &a3, &a4, &a5};
        hipLaunchCooperativeKernel((void*)lstm_scan, dim3(256), dim3(256), args, 0, stream);
    }

    // Layer 3 (reference reuses layer-2 weights)
    gemm_tn<<<gemm_grid, blk256, 0, stream>>>(H2, Wih2, bih2, bhh2, G,
                                              TSTEPS, NGATE, HDIM, nullptr, nullptr, 0);
    {
        const float* a0 = Whh2; const float* a1 = G; const float* a2 = h0_3;
        const float* a3 = c0_3; float* a4 = H3; unsigned* a5 = cnt + 2 * TSTEPS;
        void* args[] = {&a0, &a1, &a2, &a3, &a4, &a5};
        hipLaunchCooperativeKernel((void*)lstm_scan, dim3(256), dim3(256), args, 0, stream);
    }

    // Attention
    attn_dot<<<dim3(256), blk256, 0, stream>>>(H3, attn);
    softmax_1024<<<dim3(1), dim3(64), 0, stream>>>(attn);
    context_kernel<<<dim3(256), blk256, 0, stream>>>(H3, attn, out);
}

// Round 3
// 9004.466 us; speedup vs baseline: 9.9768x; 2.4185x over previous
//
#include <hip/hip_runtime.h>
#include <hip/hip_bf16.h>

// Problem constants
#define TSTEPS 1024
#define HDIM   1024
#define INDIM  512
#define NGATE  4096     // 4*HDIM

// Fused-scan grid: 64 layer-1 WGs + 128 layer-2/3 WGs, 512 threads each.
#define NWG_L1  64
#define NWG_L23 128
#define NWG_TOT 192
#define NGROUP  24      // barrier tree: 24 groups x 8 WGs
#define NSTEPS  (TSTEPS + 2)   // pipelined: layer l computes tick p-l

// ---------------------------------------------------------------------------
// Agent-scope ops: bypass L1/per-XCD-L2, hit the coherent LLC. No cache
// maintenance needed for cross-WG exchange (validated round 2, absmax 0.0).
// ---------------------------------------------------------------------------
__device__ __forceinline__ float agent_load(const float* p) {
    return __hip_atomic_load(const_cast<float*>(p), __ATOMIC_RELAXED,
                             __HIP_MEMORY_SCOPE_AGENT);
}
__device__ __forceinline__ void agent_store(float* p, float v) {
    __hip_atomic_store(p, v, __ATOMIC_RELAXED, __HIP_MEMORY_SCOPE_AGENT);
}
__device__ __forceinline__ float wave_sum64(float v) {
#pragma unroll
    for (int d = 1; d < 64; d <<= 1) v += __shfl_xor(v, d, 64);
    return v;
}
__device__ __forceinline__ float sigm(float x) { return 1.f / (1.f + __expf(-x)); }

// Two-level tree barrier, monotonic counters (one set reused every step).
// Group g's 8 arrivals for step p return old values 8p..8p+7; the last one
// bumps lvl2. Everyone spins lvl2 >= 24*(p+1). ~17 serialized RMWs vs 256.
__device__ __forceinline__ void step_barrier(unsigned* lvl1, unsigned* lvl2,
                                             int p, int wg, int tid)
{
    __syncthreads();   // drains vmcnt -> this WG's agent h-stores are at LLC
    if (tid == 0) {
        unsigned r = __hip_atomic_fetch_add(&lvl1[(wg >> 3) << 4], 1u,
                                            __ATOMIC_RELEASE, __HIP_MEMORY_SCOPE_AGENT);
        if (r == (unsigned)(8 * (p + 1) - 1))
            __hip_atomic_fetch_add(lvl2, 1u, __ATOMIC_RELEASE,
                                   __HIP_MEMORY_SCOPE_AGENT);
        const unsigned target = (unsigned)(NGROUP * (p + 1));
        while (__hip_atomic_load(lvl2, __ATOMIC_RELAXED,
                                 __HIP_MEMORY_SCOPE_AGENT) < target)
            __builtin_amdgcn_s_sleep(1);
    }
    __syncthreads();
}

// ---------------------------------------------------------------------------
// GEMM for layer-1 input gates: C[t][n] = concat(x,time)[t] . Wih1[n] + b.
// ---------------------------------------------------------------------------
#define BM 64
#define BN 64
#define BK 32

__global__ __launch_bounds__(256) void gemm_tn(
    const float* __restrict__ B,
    const float* __restrict__ bias1,
    const float* __restrict__ bias2,
    float* __restrict__ C,
    int M, int N, int K,
    const float* __restrict__ x,
    const float* __restrict__ timev)
{
    __shared__ float As[BK][BM + 4];
    __shared__ float Bs[BK][BN + 4];

    const int tid = threadIdx.x;
    const int mblocks = M / BM;
    const int bm = blockIdx.x % mblocks;
    const int bn = blockIdx.x / mblocks;
    const int t0 = bm * BM;
    const int n0 = bn * BN;

    const int tx = tid & 15;
    const int ty = tid >> 4;

    float acc[4][4] = {{0.f}};

    for (int kc = 0; kc < K; kc += BK) {
#pragma unroll
        for (int i = 0; i < 8; i++) {
            int idx = tid + i * 256;
            int r = idx >> 5;
            int c = idx & 31;
            int col = kc + c;
            int trow = t0 + r;
            float av = (col < INDIM) ? x[(size_t)trow * INDIM + col]
                                     : ((col == INDIM) ? timev[trow] : 0.f);
            As[c][r] = av;
            int nrow = n0 + r;
            Bs[c][r] = (col < K) ? B[(size_t)nrow * K + col] : 0.f;
        }
        __syncthreads();

#pragma unroll
        for (int kk = 0; kk < BK; kk++) {
            float a[4], b[4];
#pragma unroll
            for (int i = 0; i < 4; i++) a[i] = As[kk][ty * 4 + i];
#pragma unroll
            for (int j = 0; j < 4; j++) b[j] = Bs[kk][tx * 4 + j];
#pragma unroll
            for (int i = 0; i < 4; i++)
#pragma unroll
                for (int j = 0; j < 4; j++)
                    acc[i][j] = fmaf(a[i], b[j], acc[i][j]);
        }
        __syncthreads();
    }

#pragma unroll
    for (int i = 0; i < 4; i++) {
        int trow = t0 + ty * 4 + i;
#pragma unroll
        for (int j = 0; j < 4; j++) {
            int n = n0 + tx * 4 + j;
            C[(size_t)trow * N + n] = acc[i][j] + bias1[n] + bias2[n];
        }
    }
}

// ---------------------------------------------------------------------------
// Fused pipelined 3-layer scan. Global step p: layer1 tick p, layer2 tick
// p-1, layer3 tick p-2. One barrier per step (1025 total vs 3071 before).
//
// L1 WGs (wg<64): wave q owns units u0=wg*16+2q..+1. Whh1 rows in VGPRs
//   (128 regs as float2), gate inputs from precomputed G1.
// L23 WGs: wave q owns unit u=(wg-64)*8+q for BOTH layer 2 and layer 3
//   (they share Wih2/Whh2!). Holds Wih2+Whh2 rows (128 regs as float2);
//   computes gates2 = Wih2.h1[t2] + Whh2.h2[t2-1] and
//            gates3 = Wih2.h2[t3] + Whh2.h3[t3-1]; h2[t2-1]==h2[t3] shared.
// ---------------------------------------------------------------------------
__global__ __launch_bounds__(512, 2) void fused_scan(
    const float* __restrict__ Whh1,
    const float* __restrict__ G1,
    const float* __restrict__ Wih2,
    const float* __restrict__ Whh2,
    const float* __restrict__ bih2,
    const float* __restrict__ bhh2,
    const float* __restrict__ h0_1, const float* __restrict__ c0_1,
    const float* __restrict__ h0_2, const float* __restrict__ c0_2,
    const float* __restrict__ h0_3, const float* __restrict__ c0_3,
    float* __restrict__ H1, float* __restrict__ H2, float* __restrict__ H3,
    unsigned* __restrict__ lvl1, unsigned* __restrict__ lvl2)
{
    __shared__ float hs1[HDIM];
    __shared__ float hs2[HDIM];
    __shared__ float hs3[HDIM];

    const int tid = threadIdx.x;
    const int wg = blockIdx.x;
    const int q = tid >> 6;
    const int s = tid & 63;

    if (wg < NWG_L1) {
        // ----------------- Layer 1 -----------------
        const int u0 = (wg << 4) + (q << 1);
        float2 w1[2][4][8];
#pragma unroll
        for (int du = 0; du < 2; ++du)
#pragma unroll
            for (int g = 0; g < 4; ++g) {
                const float* row = Whh1 + (size_t)((g << 10) + u0 + du) * HDIM + 2 * s;
#pragma unroll
                for (int m = 0; m < 8; ++m)
                    w1[du][g][m] = *(const float2*)(row + 128 * m);
            }
        float c1[2] = {c0_1[u0], c0_1[u0 + 1]};

        for (int p = 0; p < NSTEPS; ++p) {
            if (p < TSTEPS) {
                float Gv[2][4];
#pragma unroll
                for (int du = 0; du < 2; ++du)
#pragma unroll
                    for (int g = 0; g < 4; ++g)
                        Gv[du][g] = G1[(size_t)p * NGATE + (g << 10) + u0 + du];

                const float* hp = (p == 0) ? h0_1 : (H1 + (size_t)(p - 1) * HDIM);
                float va = agent_load(hp + tid);
                float vb = agent_load(hp + tid + 512);
                hs1[tid] = va;
                hs1[tid + 512] = vb;
                __syncthreads();

                float2 acc[2][4];
#pragma unroll
                for (int du = 0; du < 2; ++du)
#pragma unroll
                    for (int g = 0; g < 4; ++g) acc[du][g] = make_float2(0.f, 0.f);
#pragma unroll
                for (int m = 0; m < 8; ++m) {
                    float2 hv = *(const float2*)&hs1[2 * s + 128 * m];
#pragma unroll
                    for (int du = 0; du < 2; ++du)
#pragma unroll
                        for (int g = 0; g < 4; ++g) {
                            acc[du][g].x = fmaf(w1[du][g][m].x, hv.x, acc[du][g].x);
                            acc[du][g].y = fmaf(w1[du][g][m].y, hv.y, acc[du][g].y);
                        }
                }
#pragma unroll
                for (int du = 0; du < 2; ++du) {
                    float gi = wave_sum64(acc[du][0].x + acc[du][0].y) + Gv[du][0];
                    float gf = wave_sum64(acc[du][1].x + acc[du][1].y) + Gv[du][1];
                    float gg = wave_sum64(acc[du][2].x + acc[du][2].y) + Gv[du][2];
                    float go = wave_sum64(acc[du][3].x + acc[du][3].y) + Gv[du][3];
                    float i_ = sigm(gi), f_ = sigm(gf), g_ = tanhf(gg), o_ = sigm(go);
                    c1[du] = f_ * c1[du] + i_ * g_;
                    float hn = o_ * tanhf(c1[du]);
                    if (s == 0)
                        agent_store(H1 + (size_t)p * HDIM + u0 + du, hn);
                }
            }
            if (p < NSTEPS - 1) step_barrier(lvl1, lvl2, p, wg, tid);
        }
    } else {
        // ----------------- Layers 2 & 3 (shared weights) -----------------
        const int u = ((wg - NWG_L1) << 3) + q;
        float2 wi[4][8], wh[4][8];
#pragma unroll
        for (int g = 0; g < 4; ++g) {
            const float* ri = Wih2 + (size_t)((g << 10) + u) * HDIM + 2 * s;
            const float* rh = Whh2 + (size_t)((g << 10) + u) * HDIM + 2 * s;
#pragma unroll
            for (int m = 0; m < 8; ++m) {
                wi[g][m] = *(const float2*)(ri + 128 * m);
                wh[g][m] = *(const float2*)(rh + 128 * m);
            }
        }
        float bias[4];
#pragma unroll
        for (int g = 0; g < 4; ++g)
            bias[g] = bih2[(g << 10) + u] + bhh2[(g << 10) + u];
        float c2 = c0_2[u], c3 = c0_3[u];

        for (int p = 0; p < NSTEPS; ++p) {
            const bool act2 = (p >= 1) && (p <= TSTEPS);
            const bool act3 = (p >= 2);
            if (act2 || act3) {
                if (act2) {
                    const float* s1 = H1 + (size_t)(p - 1) * HDIM;
                    hs1[tid]       = agent_load(s1 + tid);
                    hs1[tid + 512] = agent_load(s1 + tid + 512);
                }
                {
                    const float* s2 = (p == 1) ? h0_2 : (H2 + (size_t)(p - 2) * HDIM);
                    hs2[tid]       = agent_load(s2 + tid);
                    hs2[tid + 512] = agent_load(s2 + tid + 512);
                }
                if (act3) {
                    const float* s3 = (p == 2) ? h0_3 : (H3 + (size_t)(p - 3) * HDIM);
                    hs3[tid]       = agent_load(s3 + tid);
                    hs3[tid + 512] = agent_load(s3 + tid + 512);
                }
                __syncthreads();

                if (act2) {
                    float2 a[4], b[4];
#pragma unroll
                    for (int g = 0; g < 4; ++g) {
                        a[g] = make_float2(0.f, 0.f);
                        b[g] = make_float2(0.f, 0.f);
                    }
#pragma unroll
                    for (int m = 0; m < 8; ++m) {
                        float2 h1v = *(const float2*)&hs1[2 * s + 128 * m];
                        float2 h2v = *(const float2*)&hs2[2 * s + 128 * m];
#pragma unroll
                        for (int g = 0; g < 4; ++g) {
                            a[g].x = fmaf(wi[g][m].x, h1v.x, a[g].x);
                            a[g].y = fmaf(wi[g][m].y, h1v.y, a[g].y);
                            b[g].x = fmaf(wh[g][m].x, h2v.x, b[g].x);
                            b[g].y = fmaf(wh[g][m].y, h2v.y, b[g].y);
                        }
                    }
                    float gi = wave_sum64(a[0].x + a[0].y + b[0].x + b[0].y) + bias[0];
                    float gf = wave_sum64(a[1].x + a[1].y + b[1].x + b[1].y) + bias[1];
                    float gg = wave_sum64(a[2].x + a[2].y + b[2].x + b[2].y) + bias[2];
                    float go = wave_sum64(a[3].x + a[3].y + b[3].x + b[3].y) + bias[3];
                    float i_ = sigm(gi), f_ = sigm(gf), g_ = tanhf(gg), o_ = sigm(go);
                    c2 = f_ * c2 + i_ * g_;
                    float hn = o_ * tanhf(c2);
                    if (s == 0)
                        agent_store(H2 + (size_t)(p - 1) * HDIM + u, hn);
                }
                if (act3) {
                    float2 a[4], b[4];
#pragma unroll
                    for (int g = 0; g < 4; ++g) {
                        a[g] = make_float2(0.f, 0.f);
                        b[g] = make_float2(0.f, 0.f);
                    }
#pragma unroll
                    for (int m = 0; m < 8; ++m) {
                        float2 h2v = *(const float2*)&hs2[2 * s + 128 * m];
                        float2 h3v = *(const float2*)&hs3[2 * s + 128 * m];
#pragma unroll
                        for (int g = 0; g < 4; ++g) {
                            a[g].x = fmaf(wi[g][m].x, h2v.x, a[g].x);
                            a[g].y = fmaf(wi[g][m].y, h2v.y, a[g].y);
                            b[g].x = fmaf(wh[g][m].x, h3v.x, b[g].x);
                            b[g].y = fmaf(wh[g][m].y, h3v.y, b[g].y);
                        }
                    }
                    float gi = wave_sum64(a[0].x + a[0].y + b[0].x + b[0].y) + bias[0];
                    float gf = wave_sum64(a[1].x + a[1].y + b[1].x + b[1].y) + bias[1];
                    float gg = wave_sum64(a[2].x + a[2].y + b[2].x + b[2].y) + bias[2];
                    float go = wave_sum64(a[3].x + a[3].y + b[3].x + b[3].y) + bias[3];
                    float i_ = sigm(gi), f_ = sigm(gf), g_ = tanhf(gg), o_ = sigm(go);
                    c3 = f_ * c3 + i_ * g_;
                    float hn = o_ * tanhf(c3);
                    if (s == 0)
                        agent_store(H3 + (size_t)(p - 2) * HDIM + u, hn);
                }
            }
            if (p < NSTEPS - 1) step_barrier(lvl1, lvl2, p, wg, tid);
        }
    }
}

// ---------------------------------------------------------------------------
// Attention
// ---------------------------------------------------------------------------
__global__ __launch_bounds__(256) void attn_dot(
    const float* __restrict__ H3, float* __restrict__ attn)
{
    const int t = blockIdx.x * 4 + (threadIdx.x >> 6);
    const int lane = threadIdx.x & 63;
    const float* hrow = H3 + (size_t)t * HDIM;
    const float* hf = H3 + (size_t)(TSTEPS - 1) * HDIM;
    float p = 0.f;
    for (int j = lane; j < HDIM; j += 64) p = fmaf(hrow[j], hf[j], p);
#pragma unroll
    for (int d = 32; d; d >>= 1) p += __shfl_down(p, d, 64);
    if (lane == 0) attn[t] = p;
}

__global__ __launch_bounds__(64) void softmax_1024(float* attn)
{
    const int lane = threadIdx.x;
    float vals[16];
    float m = -1e30f;
#pragma unroll
    for (int i = 0; i < 16; i++) {
        vals[i] = attn[lane + i * 64];
        m = fmaxf(m, vals[i]);
    }
#pragma unroll
    for (int d = 32; d; d >>= 1) m = fmaxf(m, __shfl_xor(m, d, 64));
    float s = 0.f;
#pragma unroll
    for (int i = 0; i < 16; i++) {
        vals[i] = expf(vals[i] - m);
        s += vals[i];
    }
#pragma unroll
    for (int d = 32; d; d >>= 1) s += __shfl_xor(s, d, 64);
    float inv = 1.f / s;
#pragma unroll
    for (int i = 0; i < 16; i++) attn[lane + i * 64] = vals[i] * inv;
}

__global__ __launch_bounds__(256) void context_kernel(
    const float* __restrict__ H3, const float* __restrict__ w,
    float* __restrict__ out)
{
    const int u = blockIdx.x * 4 + (threadIdx.x >> 6);
    const int lane = threadIdx.x & 63;
    float p = 0.f;
    for (int t = lane; t < TSTEPS; t += 64)
        p = fmaf(H3[(size_t)t * HDIM + u], w[t], p);
#pragma unroll
    for (int d = 32; d; d >>= 1) p += __shfl_down(p, d, 64);
    if (lane == 0) out[u] = p;
}

// ---------------------------------------------------------------------------
// Launch
// ---------------------------------------------------------------------------
extern "C" void kernel_launch(void* const* d_in, const int* in_sizes, int n_in,
                              void* d_out, int out_size, void* d_ws, size_t ws_size,
                              hipStream_t stream)
{
    const float* x     = (const float*)d_in[0];
    const float* timev = (const float*)d_in[1];
    const float* h0_1  = (const float*)d_in[2];
    const float* c0_1  = (const float*)d_in[3];
    const float* h0_2  = (const float*)d_in[4];
    const float* c0_2  = (const float*)d_in[5];
    const float* h0_3  = (const float*)d_in[6];
    const float* c0_3  = (const float*)d_in[7];
    const float* Wih1  = (const float*)d_in[8];
    const float* Whh1  = (const float*)d_in[9];
    const float* bih1  = (const float*)d_in[10];
    const float* bhh1  = (const float*)d_in[11];
    const float* Wih2  = (const float*)d_in[12];
    const float* Whh2  = (const float*)d_in[13];
    const float* bih2  = (const float*)d_in[14];
    const float* bhh2  = (const float*)d_in[15];

    float* ws   = (float*)d_ws;
    float* G    = ws;                          // 1024*4096
    float* H1   = G + (size_t)TSTEPS * NGATE;
    float* H2   = H1 + (size_t)TSTEPS * HDIM;
    float* H3   = H2 + (size_t)TSTEPS * HDIM;
    float* attn = H3 + (size_t)TSTEPS * HDIM;
    unsigned* lvl1 = (unsigned*)(attn + TSTEPS);  // 24 groups * 16 uints
    unsigned* lvl2 = lvl1 + NGROUP * 16;
    float* out  = (float*)d_out;

    hipMemsetAsync(lvl1, 0, (NGROUP * 16 + 16) * sizeof(unsigned), stream);

    // Layer-1 input gates: G = concat(x,time) @ Wih1^T + bih1 + bhh1
    gemm_tn<<<dim3(1024), dim3(256), 0, stream>>>(Wih1, bih1, bhh1, G,
                                                  TSTEPS, NGATE, INDIM + 1, x, timev);

    {
        const float* a0 = Whh1;  const float* a1 = G;
        const float* a2 = Wih2;  const float* a3 = Whh2;
        const float* a4 = bih2;  const float* a5 = bhh2;
        const float* a6 = h0_1;  const float* a7 = c0_1;
        const float* a8 = h0_2;  const float* a9 = c0_2;
        const float* a10 = h0_3; const float* a11 = c0_3;
        float* a12 = H1; float* a13 = H2; float* a14 = H3;
        unsigned* a15 = lvl1; unsigned* a16 = lvl2;
        void* args[] = {&a0,&a1,&a2,&a3,&a4,&a5,&a6,&a7,&a8,&a9,&a10,&a11,
                        &a12,&a13,&a14,&a15,&a16};
        hipLaunchCooperativeKernel((void*)fused_scan, dim3(NWG_TOT), dim3(512),
                                   args, 0, stream);
    }

    // Attention
    attn_dot<<<dim3(256), dim3(256), 0, stream>>>(H3, attn);
    softmax_1024<<<dim3(1), dim3(64), 0, stream>>>(attn);
    context_kernel<<<dim3(256), dim3(256), 0, stream>>>(H3, attn, out);
}

// Round 6
// 7173.156 us; speedup vs baseline: 12.5239x; 1.2553x over previous
//
#include <hip/hip_runtime.h>

// Problem constants
#define TSTEPS 1024
#define HDIM   1024
#define INDIM  512
#define NGATE  4096     // 4*HDIM

// Fused-scan grid: 192 WGs x 1024 threads (<=256 WGs: 1 block/CU, proven
// launchable envelope — round 4/5's 384-WG coop launch failed validation).
// L1 (wg<64): 16 units/WG, wave q owns unit u0+q, all 4 gates (64 w-floats).
// L23: 8 units/WG, wave q owns unit u0+(q>>1), gate pair q&1 (64 w-floats),
//      serving BOTH layer 2 and layer 3 (shared weights).
#define NWG_L1  64
#define NWG_L23 128
#define NWG_TOT 192
#define NSTEPS  (TSTEPS + 2)   // 1026 pipeline steps
#define SPIN_MAX (1 << 22)     // deadlock safety valve: fail loud, never hang

// ---------------------------------------------------------------------------
// Agent-scope RELAXED ops only (global_load/store sc0 sc1 -> coherent LLC,
// no L2 writeback/invalidate). Ordering: __syncthreads() drains vmcnt, so a
// WG's h-stores are at the LLC before its slot signal issues.
// ---------------------------------------------------------------------------
__device__ __forceinline__ float agent_loadf(const float* p) {
    return __hip_atomic_load(const_cast<float*>(p), __ATOMIC_RELAXED,
                             __HIP_MEMORY_SCOPE_AGENT);
}
__device__ __forceinline__ void agent_storef(float* p, float v) {
    __hip_atomic_store(p, v, __ATOMIC_RELAXED, __HIP_MEMORY_SCOPE_AGENT);
}
__device__ __forceinline__ unsigned agent_loadu(const unsigned* p) {
    return __hip_atomic_load(const_cast<unsigned*>(p), __ATOMIC_RELAXED,
                             __HIP_MEMORY_SCOPE_AGENT);
}
__device__ __forceinline__ void agent_storeu(unsigned* p, unsigned v) {
    __hip_atomic_store(p, v, __ATOMIC_RELAXED, __HIP_MEMORY_SCOPE_AGENT);
}
__device__ __forceinline__ float wave_sum64(float v) {
#pragma unroll
    for (int d = 1; d < 64; d <<= 1) v += __shfl_xor(v, d, 64);
    return v;
}
__device__ __forceinline__ float sigm(float x) { return 1.f / (1.f + __expf(-x)); }

// ---------------------------------------------------------------------------
// GEMM for layer-1 input gates: G[t][n] = concat(x,time)[t] . Wih1[n] + b.
// ---------------------------------------------------------------------------
#define BM 64
#define BN 64
#define BK 32

__global__ __launch_bounds__(256) void gemm_tn(
    const float* __restrict__ B,
    const float* __restrict__ bias1,
    const float* __restrict__ bias2,
    float* __restrict__ C,
    int M, int N, int K,
    const float* __restrict__ x,
    const float* __restrict__ timev)
{
    __shared__ float As[BK][BM + 4];
    __shared__ float Bs[BK][BN + 4];

    const int tid = threadIdx.x;
    const int mblocks = M / BM;
    const int bm = blockIdx.x % mblocks;
    const int bn = blockIdx.x / mblocks;
    const int t0 = bm * BM;
    const int n0 = bn * BN;

    const int tx = tid & 15;
    const int ty = tid >> 4;

    float acc[4][4] = {{0.f}};

    for (int kc = 0; kc < K; kc += BK) {
#pragma unroll
        for (int i = 0; i < 8; i++) {
            int idx = tid + i * 256;
            int r = idx >> 5;
            int c = idx & 31;
            int col = kc + c;
            int trow = t0 + r;
            float av = (col < INDIM) ? x[(size_t)trow * INDIM + col]
                                     : ((col == INDIM) ? timev[trow] : 0.f);
            As[c][r] = av;
            int nrow = n0 + r;
            Bs[c][r] = (col < K) ? B[(size_t)nrow * K + col] : 0.f;
        }
        __syncthreads();

#pragma unroll
        for (int kk = 0; kk < BK; kk++) {
            float a[4], b[4];
#pragma unroll
            for (int i = 0; i < 4; i++) a[i] = As[kk][ty * 4 + i];
#pragma unroll
            for (int j = 0; j < 4; j++) b[j] = Bs[kk][tx * 4 + j];
#pragma unroll
            for (int i = 0; i < 4; i++)
#pragma unroll
                for (int j = 0; j < 4; j++)
                    acc[i][j] = fmaf(a[i], b[j], acc[i][j]);
        }
        __syncthreads();
    }

#pragma unroll
    for (int i = 0; i < 4; i++) {
        int trow = t0 + ty * 4 + i;
#pragma unroll
        for (int j = 0; j < 4; j++) {
            int n = n0 + tx * 4 + j;
            C[(size_t)trow * N + n] = acc[i][j] + bias1[n] + bias2[n];
        }
    }
}

// ---------------------------------------------------------------------------
// Fused pipelined 3-layer scan. Global step p: layer1 tick p, layer2 tick
// p-1, layer3 tick p-2. slot[wg] = completed steps (monotonic). Arrival =
// one relaxed agent store; wait = wave0 lane-parallel poll + ballot.
// L1 WGs wait only on L1 slots and exit after tick 1023 (slot <- NSTEPS).
// ---------------------------------------------------------------------------
__global__ __launch_bounds__(1024, 4) void fused_scan(
    const float* __restrict__ Whh1,
    const float* __restrict__ G1,
    const float* __restrict__ Wih2,
    const float* __restrict__ Whh2,
    const float* __restrict__ bih2,
    const float* __restrict__ bhh2,
    const float* __restrict__ h0_1, const float* __restrict__ c0_1,
    const float* __restrict__ h0_2, const float* __restrict__ c0_2,
    const float* __restrict__ h0_3, const float* __restrict__ c0_3,
    float* __restrict__ H1, float* __restrict__ H2, float* __restrict__ H3,
    unsigned* __restrict__ slots)
{
    __shared__ float hs1[HDIM];
    __shared__ float hs2[HDIM];
    __shared__ float hs3[HDIM];
    __shared__ float gbuf[16][4];  // L1: [unit 0..15][gate]; L23: 0-7 L2, 8-15 L3

    const int tid = threadIdx.x;
    const int wg  = blockIdx.x;
    const int q   = tid >> 6;      // wave 0..15
    const int s   = tid & 63;

    if (wg < NWG_L1) {
        // ------- Layer 1: WG owns 16 units, wave q owns unit u0+q -------
        const int u0 = wg << 4;
        const int u  = u0 + q;
        float2 w[4][8];
#pragma unroll
        for (int g = 0; g < 4; ++g) {
            const float* row = Whh1 + (size_t)((g << 10) + u) * HDIM + 2 * s;
#pragma unroll
            for (int m = 0; m < 8; ++m)
                w[g][m] = *(const float2*)(row + 128 * m);
        }
        float c1 = (tid < 16) ? c0_1[u0 + tid] : 0.f;

        for (int p = 0; p < TSTEPS; ++p) {
            float Gv0 = 0.f, Gv1 = 0.f, Gv2 = 0.f, Gv3 = 0.f;
            if (tid < 16) {   // update lanes prefetch gate inputs
                const float* gptr = G1 + (size_t)p * NGATE + u0 + tid;
                Gv0 = gptr[0];
                Gv1 = gptr[1024];
                Gv2 = gptr[2048];
                Gv3 = gptr[3072];
            }
            if (p > 0 && tid < 64) {   // poll the 64 L1 slots, 1 per lane
                const unsigned tgt = (unsigned)p;
                for (int it = 0; it < SPIN_MAX; ++it) {
                    unsigned a = agent_loadu(slots + tid);
                    if (__ballot(a >= tgt) == ~0ULL) break;
                    __builtin_amdgcn_s_sleep(2);
                }
            }
            __syncthreads();                                   // A: deps ready

            const float* hp = (p == 0) ? h0_1 : (H1 + (size_t)(p - 1) * HDIM);
            hs1[tid] = agent_loadf(hp + tid);
            __syncthreads();                                   // B: LDS staged

            float2 a0 = make_float2(0.f, 0.f), a1 = a0, a2 = a0, a3 = a0;
#pragma unroll
            for (int m = 0; m < 8; ++m) {
                float2 hv = *(const float2*)&hs1[2 * s + 128 * m];
                a0.x = fmaf(w[0][m].x, hv.x, a0.x);
                a0.y = fmaf(w[0][m].y, hv.y, a0.y);
                a1.x = fmaf(w[1][m].x, hv.x, a1.x);
                a1.y = fmaf(w[1][m].y, hv.y, a1.y);
                a2.x = fmaf(w[2][m].x, hv.x, a2.x);
                a2.y = fmaf(w[2][m].y, hv.y, a2.y);
                a3.x = fmaf(w[3][m].x, hv.x, a3.x);
                a3.y = fmaf(w[3][m].y, hv.y, a3.y);
            }
            float s0 = wave_sum64(a0.x + a0.y);
            float s1 = wave_sum64(a1.x + a1.y);
            float s2 = wave_sum64(a2.x + a2.y);
            float s3 = wave_sum64(a3.x + a3.y);
            if (s == 0) {
                gbuf[q][0] = s0;
                gbuf[q][1] = s1;
                gbuf[q][2] = s2;
                gbuf[q][3] = s3;
            }
            __syncthreads();                                   // C: sums ready

            if (tid < 16) {
                float gi = gbuf[tid][0] + Gv0;
                float gf = gbuf[tid][1] + Gv1;
                float gg = gbuf[tid][2] + Gv2;
                float go = gbuf[tid][3] + Gv3;
                float i_ = sigm(gi), f_ = sigm(gf), g_ = tanhf(gg), o_ = sigm(go);
                c1 = f_ * c1 + i_ * g_;
                float hn = o_ * tanhf(c1);
                agent_storef(H1 + (size_t)p * HDIM + u0 + tid, hn);
            }
            __syncthreads();                                   // D: stores drained
            if (tid == 0)
                agent_storeu(slots + wg, (p == TSTEPS - 1) ? (unsigned)NSTEPS
                                                           : (unsigned)(p + 1));
        }
    } else {
        // ---- Layers 2 & 3 (shared weights): WG owns 8 units ----
        const int ul = q >> 1;     // unit-local 0..7
        const int gp = q & 1;      // 0 -> gates (i,f), 1 -> gates (g,o)
        const int u0 = (wg - NWG_L1) << 3;
        const int u  = u0 + ul;
        float2 wi[2][8], wh[2][8];
#pragma unroll
        for (int j = 0; j < 2; ++j) {
            const float* ri = Wih2 + (size_t)(((2 * gp + j) << 10) + u) * HDIM + 2 * s;
            const float* rh = Whh2 + (size_t)(((2 * gp + j) << 10) + u) * HDIM + 2 * s;
#pragma unroll
            for (int m = 0; m < 8; ++m) {
                wi[j][m] = *(const float2*)(ri + 128 * m);
                wh[j][m] = *(const float2*)(rh + 128 * m);
            }
        }
        float bias0 = 0.f, bias1v = 0.f, bias2v = 0.f, bias3 = 0.f, cst = 0.f;
        if (tid < 16) {
            int uu = u0 + (tid & 7);
            bias0  = bih2[uu]        + bhh2[uu];
            bias1v = bih2[1024 + uu] + bhh2[1024 + uu];
            bias2v = bih2[2048 + uu] + bhh2[2048 + uu];
            bias3  = bih2[3072 + uu] + bhh2[3072 + uu];
            cst = (tid < 8) ? c0_2[u0 + tid] : c0_3[u0 + tid - 8];
        }

        for (int p = 0; p < NSTEPS; ++p) {
            const bool act2 = (p >= 1) && (p <= TSTEPS);
            const bool act3 = (p >= 2);

            if (p > 0 && tid < 64) {   // poll all 192 slots, 3 per lane
                const unsigned tgt = (unsigned)p;
                for (int it = 0; it < SPIN_MAX; ++it) {
                    unsigned a = agent_loadu(slots + tid);
                    unsigned b = agent_loadu(slots + tid + 64);
                    unsigned c = agent_loadu(slots + tid + 128);
                    if (__ballot((a >= tgt) && (b >= tgt) && (c >= tgt)) == ~0ULL)
                        break;
                    __builtin_amdgcn_s_sleep(2);
                }
            }
            __syncthreads();                                   // A

            if (act2)
                hs1[tid] = agent_loadf(H1 + (size_t)(p - 1) * HDIM + tid);
            if (p >= 1) {
                const float* sp = (p == 1) ? h0_2 : (H2 + (size_t)(p - 2) * HDIM);
                hs2[tid] = agent_loadf(sp + tid);
            }
            if (act3) {
                const float* sp = (p == 2) ? h0_3 : (H3 + (size_t)(p - 3) * HDIM);
                hs3[tid] = agent_loadf(sp + tid);
            }
            __syncthreads();                                   // B

            // unconditional dots; inactive prologue garbage discarded at update
            float2 p20 = make_float2(0.f, 0.f), p21 = p20, p30 = p20, p31 = p20;
#pragma unroll
            for (int m = 0; m < 8; ++m) {
                float2 h1v = *(const float2*)&hs1[2 * s + 128 * m];
                float2 h2v = *(const float2*)&hs2[2 * s + 128 * m];
                float2 h3v = *(const float2*)&hs3[2 * s + 128 * m];
                p20.x = fmaf(wi[0][m].x, h1v.x, p20.x);
                p20.y = fmaf(wi[0][m].y, h1v.y, p20.y);
                p21.x = fmaf(wi[1][m].x, h1v.x, p21.x);
                p21.y = fmaf(wi[1][m].y, h1v.y, p21.y);
                p20.x = fmaf(wh[0][m].x, h2v.x, p20.x);
                p20.y = fmaf(wh[0][m].y, h2v.y, p20.y);
                p21.x = fmaf(wh[1][m].x, h2v.x, p21.x);
                p21.y = fmaf(wh[1][m].y, h2v.y, p21.y);
                p30.x = fmaf(wi[0][m].x, h2v.x, p30.x);
                p30.y = fmaf(wi[0][m].y, h2v.y, p30.y);
                p31.x = fmaf(wi[1][m].x, h2v.x, p31.x);
                p31.y = fmaf(wi[1][m].y, h2v.y, p31.y);
                p30.x = fmaf(wh[0][m].x, h3v.x, p30.x);
                p30.y = fmaf(wh[0][m].y, h3v.y, p30.y);
                p31.x = fmaf(wh[1][m].x, h3v.x, p31.x);
                p31.y = fmaf(wh[1][m].y, h3v.y, p31.y);
            }
            float s20 = wave_sum64(p20.x + p20.y);
            float s21 = wave_sum64(p21.x + p21.y);
            float s30 = wave_sum64(p30.x + p30.y);
            float s31 = wave_sum64(p31.x + p31.y);
            if (s == 0) {
                gbuf[ul][2 * gp]          = s20;
                gbuf[ul][2 * gp + 1]      = s21;
                gbuf[8 + ul][2 * gp]      = s30;
                gbuf[8 + ul][2 * gp + 1]  = s31;
            }
            __syncthreads();                                   // C

            if (tid < 16) {
                const bool act = (tid < 8) ? act2 : act3;
                if (act) {
                    float gi = gbuf[tid][0] + bias0;
                    float gf = gbuf[tid][1] + bias1v;
                    float gg = gbuf[tid][2] + bias2v;
                    float go = gbuf[tid][3] + bias3;
                    float i_ = sigm(gi), f_ = sigm(gf), g_ = tanhf(gg), o_ = sigm(go);
                    cst = f_ * cst + i_ * g_;
                    float hn = o_ * tanhf(cst);
                    float* dst = (tid < 8)
                        ? (H2 + (size_t)(p - 1) * HDIM + u0 + tid)
                        : (H3 + (size_t)(p - 2) * HDIM + u0 + (tid - 8));
                    agent_storef(dst, hn);
                }
            }
            __syncthreads();                                   // D
            if (tid == 0 && p < NSTEPS - 1)
                agent_storeu(slots + wg, (unsigned)(p + 1));
        }
    }
}

// ---------------------------------------------------------------------------
// Attention
// ---------------------------------------------------------------------------
__global__ __launch_bounds__(256) void attn_dot(
    const float* __restrict__ H3, float* __restrict__ attn)
{
    const int t = blockIdx.x * 4 + (threadIdx.x >> 6);
    const int lane = threadIdx.x & 63;
    const float* hrow = H3 + (size_t)t * HDIM;
    const float* hf = H3 + (size_t)(TSTEPS - 1) * HDIM;
    float p = 0.f;
    for (int j = lane; j < HDIM; j += 64) p = fmaf(hrow[j], hf[j], p);
#pragma unroll
    for (int d = 32; d; d >>= 1) p += __shfl_down(p, d, 64);
    if (lane == 0) attn[t] = p;
}

__global__ __launch_bounds__(64) void softmax_1024(float* attn)
{
    const int lane = threadIdx.x;
    float vals[16];
    float m = -1e30f;
#pragma unroll
    for (int i = 0; i < 16; i++) {
        vals[i] = attn[lane + i * 64];
        m = fmaxf(m, vals[i]);
    }
#pragma unroll
    for (int d = 32; d; d >>= 1) m = fmaxf(m, __shfl_xor(m, d, 64));
    float s = 0.f;
#pragma unroll
    for (int i = 0; i < 16; i++) {
        vals[i] = expf(vals[i] - m);
        s += vals[i];
    }
#pragma unroll
    for (int d = 32; d; d >>= 1) s += __shfl_xor(s, d, 64);
    float inv = 1.f / s;
#pragma unroll
    for (int i = 0; i < 16; i++) attn[lane + i * 64] = vals[i] * inv;
}

__global__ __launch_bounds__(256) void context_kernel(
    const float* __restrict__ H3, const float* __restrict__ w,
    float* __restrict__ out)
{
    const int u = blockIdx.x * 4 + (threadIdx.x >> 6);
    const int lane = threadIdx.x & 63;
    float p = 0.f;
    for (int t = lane; t < TSTEPS; t += 64)
        p = fmaf(H3[(size_t)t * HDIM + u], w[t], p);
#pragma unroll
    for (int d = 32; d; d >>= 1) p += __shfl_down(p, d, 64);
    if (lane == 0) out[u] = p;
}

// ---------------------------------------------------------------------------
// Launch
// ---------------------------------------------------------------------------
extern "C" void kernel_launch(void* const* d_in, const int* in_sizes, int n_in,
                              void* d_out, int out_size, void* d_ws, size_t ws_size,
                              hipStream_t stream)
{
    const float* x     = (const float*)d_in[0];
    const float* timev = (const float*)d_in[1];
    const float* h0_1  = (const float*)d_in[2];
    const float* c0_1  = (const float*)d_in[3];
    const float* h0_2  = (const float*)d_in[4];
    const float* c0_2  = (const float*)d_in[5];
    const float* h0_3  = (const float*)d_in[6];
    const float* c0_3  = (const float*)d_in[7];
    const float* Wih1  = (const float*)d_in[8];
    const float* Whh1  = (const float*)d_in[9];
    const float* bih1  = (const float*)d_in[10];
    const float* bhh1  = (const float*)d_in[11];
    const float* Wih2  = (const float*)d_in[12];
    const float* Whh2  = (const float*)d_in[13];
    const float* bih2  = (const float*)d_in[14];
    const float* bhh2  = (const float*)d_in[15];

    float* ws   = (float*)d_ws;
    float* G    = ws;                          // 1024*4096
    float* H1   = G + (size_t)TSTEPS * NGATE;
    float* H2   = H1 + (size_t)TSTEPS * HDIM;
    float* H3   = H2 + (size_t)TSTEPS * HDIM;
    float* attn = H3 + (size_t)TSTEPS * HDIM;
    unsigned* slots = (unsigned*)(attn + TSTEPS);
    float* out  = (float*)d_out;

    hipMemsetAsync(slots, 0, NWG_TOT * sizeof(unsigned), stream);

    // Layer-1 input gates: G = concat(x,time) @ Wih1^T + bih1 + bhh1
    gemm_tn<<<dim3(1024), dim3(256), 0, stream>>>(Wih1, bih1, bhh1, G,
                                                  TSTEPS, NGATE, INDIM + 1, x, timev);

    {
        const float* a0 = Whh1;  const float* a1 = G;
        const float* a2 = Wih2;  const float* a3 = Whh2;
        const float* a4 = bih2;  const float* a5 = bhh2;
        const float* a6 = h0_1;  const float* a7 = c0_1;
        const float* a8 = h0_2;  const float* a9 = c0_2;
        const float* a10 = h0_3; const float* a11 = c0_3;
        float* a12 = H1; float* a13 = H2; float* a14 = H3;
        unsigned* a15 = slots;
        void* args[] = {&a0,&a1,&a2,&a3,&a4,&a5,&a6,&a7,&a8,&a9,&a10,&a11,
                        &a12,&a13,&a14,&a15};
        hipLaunchCooperativeKernel((void*)fused_scan, dim3(NWG_TOT), dim3(1024),
                                   args, 0, stream);
    }

    // Attention
    attn_dot<<<dim3(256), dim3(256), 0, stream>>>(H3, attn);
    softmax_1024<<<dim3(1), dim3(64), 0, stream>>>(attn);
    context_kernel<<<dim3(256), dim3(256), 0, stream>>>(H3, attn, out);
}

// Round 7
// 4741.122 us; speedup vs baseline: 18.9483x; 1.5130x over previous
//
#include <hip/hip_runtime.h>

// Problem constants
#define TSTEPS 1024
#define HDIM   1024
#define INDIM  512
#define NGATE  4096     // 4*HDIM

// Fused-scan grid: 192 WGs x 1024 threads (proven-launchable coop envelope).
// L1 (wg<64): 16 units/WG, wave q owns unit u0+q, all 4 gates.
// L23: 8 units/WG, wave q owns unit u0+(q>>1), gate pair q&1, serving BOTH
//      layer 2 and layer 3 (shared weights).
#define NWG_L1  64
#define NWG_L23 128
#define NWG_TOT 192
#define POISON  0xAAAAAAAAu
#define SPIN_MAX (1 << 20)   // deadlock valve: fail loud, never hang

// ---------------------------------------------------------------------------
// Agent-scope RELAXED ops (global sc0 sc1 -> coherent LLC, no cache maint).
// NO flags, NO barrier: H1/H2/H3 are pre-poisoned 0xAA; a consumer polls the
// exact row it needs until no lane sees the poison pattern. The poll IS the
// data load — one LLC round trip per dependency, self-throttling (stops the
// moment data lands), no hot flag lines. Rounds 2/3/6 showed ~6.5-8.6us/step
// across three flag-based barriers -> flag mechanics were never the cost;
// the serialized flag+data LLC round-trips and UC poll contention were.
// ---------------------------------------------------------------------------
__device__ __forceinline__ float agent_loadf(const float* p) {
    return __hip_atomic_load(const_cast<float*>(p), __ATOMIC_RELAXED,
                             __HIP_MEMORY_SCOPE_AGENT);
}
__device__ __forceinline__ void agent_storef(float* p, float v) {
    __hip_atomic_store(p, v, __ATOMIC_RELAXED, __HIP_MEMORY_SCOPE_AGENT);
}
// Wave-cooperative poll: each lane owns one dword of a 64-dword segment;
// loop until no lane's dword is poison. Returns the (valid) value.
__device__ __forceinline__ float poll_row(const float* p) {
    float v = 0.f;
    for (int it = 0; it < SPIN_MAX; ++it) {
        v = agent_loadf(p);
        if (__ballot(__float_as_uint(v) == POISON) == 0ULL) break;
        __builtin_amdgcn_s_sleep(1);
    }
    return v;
}
__device__ __forceinline__ float wave_sum64(float v) {
#pragma unroll
    for (int d = 1; d < 64; d <<= 1) v += __shfl_xor(v, d, 64);
    return v;
}
__device__ __forceinline__ float sigm(float x) { return 1.f / (1.f + __expf(-x)); }

// ---------------------------------------------------------------------------
// GEMM for layer-1 input gates: G[t][n] = concat(x,time)[t] . Wih1[n] + b.
// ---------------------------------------------------------------------------
#define BM 64
#define BN 64
#define BK 32

__global__ __launch_bounds__(256) void gemm_tn(
    const float* __restrict__ B,
    const float* __restrict__ bias1,
    const float* __restrict__ bias2,
    float* __restrict__ C,
    int M, int N, int K,
    const float* __restrict__ x,
    const float* __restrict__ timev)
{
    __shared__ float As[BK][BM + 4];
    __shared__ float Bs[BK][BN + 4];

    const int tid = threadIdx.x;
    const int mblocks = M / BM;
    const int bm = blockIdx.x % mblocks;
    const int bn = blockIdx.x / mblocks;
    const int t0 = bm * BM;
    const int n0 = bn * BN;

    const int tx = tid & 15;
    const int ty = tid >> 4;

    float acc[4][4] = {{0.f}};

    for (int kc = 0; kc < K; kc += BK) {
#pragma unroll
        for (int i = 0; i < 8; i++) {
            int idx = tid + i * 256;
            int r = idx >> 5;
            int c = idx & 31;
            int col = kc + c;
            int trow = t0 + r;
            float av = (col < INDIM) ? x[(size_t)trow * INDIM + col]
                                     : ((col == INDIM) ? timev[trow] : 0.f);
            As[c][r] = av;
            int nrow = n0 + r;
            Bs[c][r] = (col < K) ? B[(size_t)nrow * K + col] : 0.f;
        }
        __syncthreads();

#pragma unroll
        for (int kk = 0; kk < BK; kk++) {
            float a[4], b[4];
#pragma unroll
            for (int i = 0; i < 4; i++) a[i] = As[kk][ty * 4 + i];
#pragma unroll
            for (int j = 0; j < 4; j++) b[j] = Bs[kk][tx * 4 + j];
#pragma unroll
            for (int i = 0; i < 4; i++)
#pragma unroll
                for (int j = 0; j < 4; j++)
                    acc[i][j] = fmaf(a[i], b[j], acc[i][j]);
        }
        __syncthreads();
    }

#pragma unroll
    for (int i = 0; i < 4; i++) {
        int trow = t0 + ty * 4 + i;
#pragma unroll
        for (int j = 0; j < 4; j++) {
            int n = n0 + tx * 4 + j;
            C[(size_t)trow * N + n] = acc[i][j] + bias1[n] + bias2[n];
        }
    }
}

// ---------------------------------------------------------------------------
// Fused dataflow 3-layer scan. No barriers, no flags: consumers poll the
// poisoned H rows directly. Each WG advances as soon as its inputs exist.
// ---------------------------------------------------------------------------
__global__ __launch_bounds__(1024, 4) void fused_scan(
    const float* __restrict__ Whh1,
    const float* __restrict__ G1,
    const float* __restrict__ Wih2,
    const float* __restrict__ Whh2,
    const float* __restrict__ bih2,
    const float* __restrict__ bhh2,
    const float* __restrict__ h0_1, const float* __restrict__ c0_1,
    const float* __restrict__ h0_2, const float* __restrict__ c0_2,
    const float* __restrict__ h0_3, const float* __restrict__ c0_3,
    float* __restrict__ H1, float* __restrict__ H2, float* __restrict__ H3)
{
    __shared__ float hs1[HDIM];
    __shared__ float hs2[HDIM];
    __shared__ float hs3[HDIM];
    __shared__ float gbuf[16][4];  // L1: [unit 0..15][gate]; L23: 0-7 L2, 8-15 L3

    const int tid = threadIdx.x;
    const int wg  = blockIdx.x;
    const int q   = tid >> 6;      // wave 0..15
    const int s   = tid & 63;

    if (wg < NWG_L1) {
        // ------- Layer 1: WG owns 16 units, wave q owns unit u0+q -------
        const int u0 = wg << 4;
        const int u  = u0 + q;
        float2 w[4][8];
#pragma unroll
        for (int g = 0; g < 4; ++g) {
            const float* row = Whh1 + (size_t)((g << 10) + u) * HDIM + 2 * s;
#pragma unroll
            for (int m = 0; m < 8; ++m)
                w[g][m] = *(const float2*)(row + 128 * m);
        }
        float c1 = (tid < 16) ? c0_1[u0 + tid] : 0.f;

        for (int t = 0; t < TSTEPS; ++t) {
            float Gv0 = 0.f, Gv1 = 0.f, Gv2 = 0.f, Gv3 = 0.f;
            if (tid < 16) {   // prefetch gate inputs (normal cached loads)
                const float* gptr = G1 + (size_t)t * NGATE + u0 + tid;
                Gv0 = gptr[0];
                Gv1 = gptr[1024];
                Gv2 = gptr[2048];
                Gv3 = gptr[3072];
            }
            // stage h1[t-1]: poll the data itself (peers' dwords arrive async)
            hs1[tid] = (t == 0) ? h0_1[tid]
                               : poll_row(H1 + (size_t)(t - 1) * HDIM + tid);
            __syncthreads();                                   // A: staged

            float2 a0 = make_float2(0.f, 0.f), a1 = a0, a2 = a0, a3 = a0;
#pragma unroll
            for (int m = 0; m < 8; ++m) {
                float2 hv = *(const float2*)&hs1[2 * s + 128 * m];
                a0.x = fmaf(w[0][m].x, hv.x, a0.x);
                a0.y = fmaf(w[0][m].y, hv.y, a0.y);
                a1.x = fmaf(w[1][m].x, hv.x, a1.x);
                a1.y = fmaf(w[1][m].y, hv.y, a1.y);
                a2.x = fmaf(w[2][m].x, hv.x, a2.x);
                a2.y = fmaf(w[2][m].y, hv.y, a2.y);
                a3.x = fmaf(w[3][m].x, hv.x, a3.x);
                a3.y = fmaf(w[3][m].y, hv.y, a3.y);
            }
            float s0 = wave_sum64(a0.x + a0.y);
            float s1 = wave_sum64(a1.x + a1.y);
            float s2 = wave_sum64(a2.x + a2.y);
            float s3 = wave_sum64(a3.x + a3.y);
            if (s == 0) {
                gbuf[q][0] = s0;
                gbuf[q][1] = s1;
                gbuf[q][2] = s2;
                gbuf[q][3] = s3;
            }
            __syncthreads();                                   // B: sums ready

            if (tid < 16) {
                float gi = gbuf[tid][0] + Gv0;
                float gf = gbuf[tid][1] + Gv1;
                float gg = gbuf[tid][2] + Gv2;
                float go = gbuf[tid][3] + Gv3;
                float i_ = sigm(gi), f_ = sigm(gf), g_ = tanhf(gg), o_ = sigm(go);
                c1 = f_ * c1 + i_ * g_;
                float hn = o_ * tanhf(c1);
                agent_storef(H1 + (size_t)t * HDIM + u0 + tid, hn);
            }
            // no drain, no flag: the stored dwords ARE the signal
        }
    } else {
        // ---- Layers 2 & 3 (shared weights): WG owns 8 units ----
        const int ul = q >> 1;     // unit-local 0..7
        const int gp = q & 1;      // 0 -> gates (i,f), 1 -> gates (g,o)
        const int u0 = (wg - NWG_L1) << 3;
        const int u  = u0 + ul;
        float2 wi[2][8], wh[2][8];
#pragma unroll
        for (int j = 0; j < 2; ++j) {
            const float* ri = Wih2 + (size_t)(((2 * gp + j) << 10) + u) * HDIM + 2 * s;
            const float* rh = Whh2 + (size_t)(((2 * gp + j) << 10) + u) * HDIM + 2 * s;
#pragma unroll
            for (int m = 0; m < 8; ++m) {
                wi[j][m] = *(const float2*)(ri + 128 * m);
                wh[j][m] = *(const float2*)(rh + 128 * m);
            }
        }
        float bias0 = 0.f, bias1v = 0.f, bias2v = 0.f, bias3 = 0.f, cst = 0.f;
        if (tid < 16) {
            int uu = u0 + (tid & 7);
            bias0  = bih2[uu]        + bhh2[uu];
            bias1v = bih2[1024 + uu] + bhh2[1024 + uu];
            bias2v = bih2[2048 + uu] + bhh2[2048 + uu];
            bias3  = bih2[3072 + uu] + bhh2[3072 + uu];
            cst = (tid < 8) ? c0_2[u0 + tid] : c0_3[u0 + tid - 8];
        }

        // iteration t: layer2 tick t (needs h1[t], h2[t-1]) and
        //              layer3 tick t-1 (needs h2[t-1], h3[t-2])
        for (int t = 0; t <= TSTEPS; ++t) {
            const bool do2 = (t < TSTEPS);
            const bool do3 = (t >= 1);

            if (do2)
                hs1[tid] = poll_row(H1 + (size_t)t * HDIM + tid);
            hs2[tid] = (t == 0) ? h0_2[tid]
                                : poll_row(H2 + (size_t)(t - 1) * HDIM + tid);
            if (do3)
                hs3[tid] = (t == 1) ? h0_3[tid]
                                    : poll_row(H3 + (size_t)(t - 2) * HDIM + tid);
            __syncthreads();                                   // A: staged

            // unconditional dots; inactive-edge garbage discarded at update
            float2 p20 = make_float2(0.f, 0.f), p21 = p20, p30 = p20, p31 = p20;
#pragma unroll
            for (int m = 0; m < 8; ++m) {
                float2 h1v = *(const float2*)&hs1[2 * s + 128 * m];
                float2 h2v = *(const float2*)&hs2[2 * s + 128 * m];
                float2 h3v = *(const float2*)&hs3[2 * s + 128 * m];
                p20.x = fmaf(wi[0][m].x, h1v.x, p20.x);
                p20.y = fmaf(wi[0][m].y, h1v.y, p20.y);
                p21.x = fmaf(wi[1][m].x, h1v.x, p21.x);
                p21.y = fmaf(wi[1][m].y, h1v.y, p21.y);
                p20.x = fmaf(wh[0][m].x, h2v.x, p20.x);
                p20.y = fmaf(wh[0][m].y, h2v.y, p20.y);
                p21.x = fmaf(wh[1][m].x, h2v.x, p21.x);
                p21.y = fmaf(wh[1][m].y, h2v.y, p21.y);
                p30.x = fmaf(wi[0][m].x, h2v.x, p30.x);
                p30.y = fmaf(wi[0][m].y, h2v.y, p30.y);
                p31.x = fmaf(wi[1][m].x, h2v.x, p31.x);
                p31.y = fmaf(wi[1][m].y, h2v.y, p31.y);
                p30.x = fmaf(wh[0][m].x, h3v.x, p30.x);
                p30.y = fmaf(wh[0][m].y, h3v.y, p30.y);
                p31.x = fmaf(wh[1][m].x, h3v.x, p31.x);
                p31.y = fmaf(wh[1][m].y, h3v.y, p31.y);
            }
            float s20 = wave_sum64(p20.x + p20.y);
            float s21 = wave_sum64(p21.x + p21.y);
            float s30 = wave_sum64(p30.x + p30.y);
            float s31 = wave_sum64(p31.x + p31.y);
            if (s == 0) {
                gbuf[ul][2 * gp]          = s20;
                gbuf[ul][2 * gp + 1]      = s21;
                gbuf[8 + ul][2 * gp]      = s30;
                gbuf[8 + ul][2 * gp + 1]  = s31;
            }
            __syncthreads();                                   // B: sums ready

            if (tid < 16) {
                const bool act = (tid < 8) ? do2 : do3;
                if (act) {
                    float gi = gbuf[tid][0] + bias0;
                    float gf = gbuf[tid][1] + bias1v;
                    float gg = gbuf[tid][2] + bias2v;
                    float go = gbuf[tid][3] + bias3;
                    float i_ = sigm(gi), f_ = sigm(gf), g_ = tanhf(gg), o_ = sigm(go);
                    cst = f_ * cst + i_ * g_;
                    float hn = o_ * tanhf(cst);
                    float* dst = (tid < 8)
                        ? (H2 + (size_t)t * HDIM + u0 + tid)
                        : (H3 + (size_t)(t - 1) * HDIM + u0 + (tid - 8));
                    agent_storef(dst, hn);
                }
            }
        }
    }
}

// ---------------------------------------------------------------------------
// Attention
// ---------------------------------------------------------------------------
__global__ __launch_bounds__(256) void attn_dot(
    const float* __restrict__ H3, float* __restrict__ attn)
{
    const int t = blockIdx.x * 4 + (threadIdx.x >> 6);
    const int lane = threadIdx.x & 63;
    const float* hrow = H3 + (size_t)t * HDIM;
    const float* hf = H3 + (size_t)(TSTEPS - 1) * HDIM;
    float p = 0.f;
    for (int j = lane; j < HDIM; j += 64) p = fmaf(hrow[j], hf[j], p);
#pragma unroll
    for (int d = 32; d; d >>= 1) p += __shfl_down(p, d, 64);
    if (lane == 0) attn[t] = p;
}

__global__ __launch_bounds__(64) void softmax_1024(float* attn)
{
    const int lane = threadIdx.x;
    float vals[16];
    float m = -1e30f;
#pragma unroll
    for (int i = 0; i < 16; i++) {
        vals[i] = attn[lane + i * 64];
        m = fmaxf(m, vals[i]);
    }
#pragma unroll
    for (int d = 32; d; d >>= 1) m = fmaxf(m, __shfl_xor(m, d, 64));
    float s = 0.f;
#pragma unroll
    for (int i = 0; i < 16; i++) {
        vals[i] = expf(vals[i] - m);
        s += vals[i];
    }
#pragma unroll
    for (int d = 32; d; d >>= 1) s += __shfl_xor(s, d, 64);
    float inv = 1.f / s;
#pragma unroll
    for (int i = 0; i < 16; i++) attn[lane + i * 64] = vals[i] * inv;
}

__global__ __launch_bounds__(256) void context_kernel(
    const float* __restrict__ H3, const float* __restrict__ w,
    float* __restrict__ out)
{
    const int u = blockIdx.x * 4 + (threadIdx.x >> 6);
    const int lane = threadIdx.x & 63;
    float p = 0.f;
    for (int t = lane; t < TSTEPS; t += 64)
        p = fmaf(H3[(size_t)t * HDIM + u], w[t], p);
#pragma unroll
    for (int d = 32; d; d >>= 1) p += __shfl_down(p, d, 64);
    if (lane == 0) out[u] = p;
}

// ---------------------------------------------------------------------------
// Launch
// ---------------------------------------------------------------------------
extern "C" void kernel_launch(void* const* d_in, const int* in_sizes, int n_in,
                              void* d_out, int out_size, void* d_ws, size_t ws_size,
                              hipStream_t stream)
{
    const float* x     = (const float*)d_in[0];
    const float* timev = (const float*)d_in[1];
    const float* h0_1  = (const float*)d_in[2];
    const float* c0_1  = (const float*)d_in[3];
    const float* h0_2  = (const float*)d_in[4];
    const float* c0_2  = (const float*)d_in[5];
    const float* h0_3  = (const float*)d_in[6];
    const float* c0_3  = (const float*)d_in[7];
    const float* Wih1  = (const float*)d_in[8];
    const float* Whh1  = (const float*)d_in[9];
    const float* bih1  = (const float*)d_in[10];
    const float* bhh1  = (const float*)d_in[11];
    const float* Wih2  = (const float*)d_in[12];
    const float* Whh2  = (const float*)d_in[13];
    const float* bih2  = (const float*)d_in[14];
    const float* bhh2  = (const float*)d_in[15];

    float* ws   = (float*)d_ws;
    float* G    = ws;                          // 1024*4096
    float* H1   = G + (size_t)TSTEPS * NGATE;
    float* H2   = H1 + (size_t)TSTEPS * HDIM;
    float* H3   = H2 + (size_t)TSTEPS * HDIM;
    float* attn = H3 + (size_t)TSTEPS * HDIM;
    float* out  = (float*)d_out;

    // Ensure H1..H3 hold the poison pattern regardless of harness semantics
    // (they are contiguous). The poll protocol depends on it.
    hipMemsetAsync(H1, 0xAA, (size_t)3 * TSTEPS * HDIM * sizeof(float), stream);

    // Layer-1 input gates: G = concat(x,time) @ Wih1^T + bih1 + bhh1
    gemm_tn<<<dim3(1024), dim3(256), 0, stream>>>(Wih1, bih1, bhh1, G,
                                                  TSTEPS, NGATE, INDIM + 1, x, timev);

    {
        const float* a0 = Whh1;  const float* a1 = G;
        const float* a2 = Wih2;  const float* a3 = Whh2;
        const float* a4 = bih2;  const float* a5 = bhh2;
        const float* a6 = h0_1;  const float* a7 = c0_1;
        const float* a8 = h0_2;  const float* a9 = c0_2;
        const float* a10 = h0_3; const float* a11 = c0_3;
        float* a12 = H1; float* a13 = H2; float* a14 = H3;
        void* args[] = {&a0,&a1,&a2,&a3,&a4,&a5,&a6,&a7,&a8,&a9,&a10,&a11,
                        &a12,&a13,&a14};
        hipLaunchCooperativeKernel((void*)fused_scan, dim3(NWG_TOT), dim3(1024),
                                   args, 0, stream);
    }

    // Attention
    attn_dot<<<dim3(256), dim3(256), 0, stream>>>(H3, attn);
    softmax_1024<<<dim3(1), dim3(64), 0, stream>>>(attn);
    context_kernel<<<dim3(256), dim3(256), 0, stream>>>(H3, attn, out);
}